// Round 1
// baseline (998.542 us; speedup 1.0000x reference)
//
#include <hip/hip_runtime.h>
#include <hip/hip_bf16.h>

#define E_TOT   1600000
#define NN      50000
#define K1      176     // msg MLP input dim (2*64+32+16)
#define H1      128     // MSG_HID
#define H2      64      // MSG_OUT
#define H3      64      // MOV_HID
#define TE      64      // edges per tile
#define AS      200     // m_in LDS row stride (bf16 elems), 400B: bank-friendly, 16B aligned
#define HS      136     // h LDS row stride, 272B
#define MS      72      // msg LDS row stride, 144B

typedef __attribute__((ext_vector_type(8))) short bf16x8;
typedef __attribute__((ext_vector_type(4))) float f32x4;

__device__ __forceinline__ unsigned short f2bf(float x) {
  unsigned u = __builtin_bit_cast(unsigned, x);
  return (unsigned short)((u + 0x7FFFu + ((u >> 16) & 1u)) >> 16);   // RNE
}
__device__ __forceinline__ float silu_f(float x) { return x / (1.0f + __expf(-x)); }

// ---------------------------------------------------------------------------
// Edge kernel: per 64-edge tile, build m_in (bf16), 3 chained MFMA GEMMs,
// atomic scatter of msg -> msg_tot and rel*s -> out_coord.
// Weight fragments live in LDS, loaded once per (persistent) block.
// Fragment convention (16x16x32 bf16): A elem j of lane l = A[l%16][k0+(l/16)*8+j],
// B elem j = B[k0+(l/16)*8+j][l%16]  (same k-map for A and B => permutation-safe).
// C/D: col = lane&15, row = (lane>>4)*4 + reg   (HW-verified).
// ---------------------------------------------------------------------------
__global__ __launch_bounds__(256, 1) void egnn_edge(
    const float* __restrict__ node_feat, const float* __restrict__ coord,
    const float* __restrict__ edge_feat, const int* __restrict__ eidx,
    const float* __restrict__ w1_msg, const float* __restrict__ w2_msg,
    const float* __restrict__ w1_mov, const float* __restrict__ w2_mov,
    const float* __restrict__ rbf_c,
    float* __restrict__ msg_tot, float* __restrict__ out_coord)
{
  __shared__ unsigned short w1f[6*8*64*8];   // [kb<6][nt<8][lane][8]  48KB
  __shared__ unsigned short w2f[4*4*64*8];   // 16KB
  __shared__ unsigned short w3f[2*4*64*8];   // 8KB
  __shared__ unsigned short a_lds[TE*AS];    // 25.6KB
  __shared__ unsigned short h_lds[TE*HS];    // 17.4KB
  __shared__ unsigned short m_lds[TE*MS];    // 9.2KB
  __shared__ int   sidx[TE];
  __shared__ int   didx[TE];
  __shared__ float relv[3][TE];
  __shared__ float distv[TE];
  __shared__ float w2m[H3];
  __shared__ float rbfc[32];

  const int t = threadIdx.x;
  const int lane = t & 63;
  const int wv = t >> 6;                 // wave id 0..3, owns rows 16*wv..+15

  // ---- stage weight fragments (once per block) ----
  for (int i = t; i < 6*8*64*8; i += 256) {
    int j = i & 7, l = (i >> 3) & 63, nt = (i >> 9) & 7, kb = i >> 12;
    int k = kb*32 + (l >> 4)*8 + j;
    int n = nt*16 + (l & 15);
    w1f[i] = f2bf(k < K1 ? w1_msg[k*H1 + n] : 0.0f);
  }
  for (int i = t; i < 4*4*64*8; i += 256) {
    int j = i & 7, l = (i >> 3) & 63, nt = (i >> 9) & 3, kb = i >> 11;
    w2f[i] = f2bf(w2_msg[(kb*32 + (l >> 4)*8 + j)*H2 + nt*16 + (l & 15)]);
  }
  for (int i = t; i < 2*4*64*8; i += 256) {
    int j = i & 7, l = (i >> 3) & 63, nt = (i >> 9) & 3, kb = i >> 11;
    w3f[i] = f2bf(w1_mov[(kb*32 + (l >> 4)*8 + j)*H3 + nt*16 + (l & 15)]);
  }
  if (t < H3) w2m[t] = w2_mov[t];
  if (t < 32) rbfc[t] = rbf_c[t];

  const int row16 = wv*16 + (lane & 15);   // A-frag row for this lane
  const int g8 = (lane >> 4) * 8;          // k sub-offset
  const int orow = wv*16 + (lane >> 4)*4;  // C rows base
  const int ocol = lane & 15;              // C col

  for (int tile = blockIdx.x; tile < E_TOT / TE; tile += gridDim.x) {
    const int e0 = tile * TE;
    __syncthreads();                       // protect LDS reuse across iterations
    if (t < TE) {
      sidx[t] = eidx[e0 + t];
      didx[t] = eidx[E_TOT + e0 + t];
    }
    __syncthreads();
    // ---- stage m_in: [src feat 0:64 | dst feat 64:128 | rbf 128:160 | ef 160:176 | pad]
    {
      const int e = t >> 2, q = t & 3;
      unsigned short* arow = a_lds + e*AS;
      const float4* ps = (const float4*)(node_feat + sidx[e]*64 + q*16);
      const float4* pd = (const float4*)(node_feat + didx[e]*64 + q*16);
      #pragma unroll
      for (int qq = 0; qq < 4; ++qq) {
        float4 v = ps[qq]; int c = q*16 + qq*4;
        arow[c] = f2bf(v.x); arow[c+1] = f2bf(v.y); arow[c+2] = f2bf(v.z); arow[c+3] = f2bf(v.w);
      }
      #pragma unroll
      for (int qq = 0; qq < 4; ++qq) {
        float4 v = pd[qq]; int c = 64 + q*16 + qq*4;
        arow[c] = f2bf(v.x); arow[c+1] = f2bf(v.y); arow[c+2] = f2bf(v.z); arow[c+3] = f2bf(v.w);
      }
      float4 ef = ((const float4*)(edge_feat + (e0 + e)*16))[q];
      int c = 160 + q*4;
      arow[c] = f2bf(ef.x); arow[c+1] = f2bf(ef.y); arow[c+2] = f2bf(ef.z); arow[c+3] = f2bf(ef.w);
      if (t < TE) {
        int s = sidx[t], d = didx[t];
        float ax = coord[d*3+0] - coord[s*3+0];
        float ay = coord[d*3+1] - coord[s*3+1];
        float az = coord[d*3+2] - coord[s*3+2];
        relv[0][t] = ax; relv[1][t] = ay; relv[2][t] = az;
        distv[t] = sqrtf(ax*ax + ay*ay + az*az);
      }
    }
    __syncthreads();
    {
      const int e = t >> 2, q = t & 3;
      unsigned short* arow = a_lds + e*AS;
      float dd = distv[e];
      #pragma unroll
      for (int j = 0; j < 8; ++j) {
        float df = dd - rbfc[q*8 + j];
        arow[128 + q*8 + j] = f2bf(__expf(-10.0f * df * df));
      }
      int c = 176 + q*4;                   // zero K-pad 176..191
      arow[c] = 0; arow[c+1] = 0; arow[c+2] = 0; arow[c+3] = 0;
    }
    __syncthreads();
    // ---- GEMM1: h = silu(m_in @ W1)  [64x192]@[192x128]
    {
      const f32x4 z4 = {0.f, 0.f, 0.f, 0.f};
      f32x4 acc[8];
      #pragma unroll
      for (int nt = 0; nt < 8; ++nt) acc[nt] = z4;
      #pragma unroll
      for (int kb = 0; kb < 6; ++kb) {
        bf16x8 af = *(const bf16x8*)(a_lds + row16*AS + kb*32 + g8);
        #pragma unroll
        for (int nt = 0; nt < 8; ++nt) {
          bf16x8 bfv = *(const bf16x8*)(w1f + ((kb*8 + nt)*64 + lane)*8);
          acc[nt] = __builtin_amdgcn_mfma_f32_16x16x32_bf16(af, bfv, acc[nt], 0, 0, 0);
        }
      }
      #pragma unroll
      for (int nt = 0; nt < 8; ++nt)
        #pragma unroll
        for (int r = 0; r < 4; ++r)
          h_lds[(orow + r)*HS + nt*16 + ocol] = f2bf(silu_f(acc[nt][r]));
    }
    __syncthreads();
    // ---- GEMM2: msg = silu(h @ W2)  [64x128]@[128x64]; scatter msg
    {
      const f32x4 z4 = {0.f, 0.f, 0.f, 0.f};
      f32x4 acc[4];
      #pragma unroll
      for (int nt = 0; nt < 4; ++nt) acc[nt] = z4;
      #pragma unroll
      for (int kb = 0; kb < 4; ++kb) {
        bf16x8 af = *(const bf16x8*)(h_lds + row16*HS + kb*32 + g8);
        #pragma unroll
        for (int nt = 0; nt < 4; ++nt) {
          bf16x8 bfv = *(const bf16x8*)(w2f + ((kb*4 + nt)*64 + lane)*8);
          acc[nt] = __builtin_amdgcn_mfma_f32_16x16x32_bf16(af, bfv, acc[nt], 0, 0, 0);
        }
      }
      #pragma unroll
      for (int nt = 0; nt < 4; ++nt) {
        #pragma unroll
        for (int r = 0; r < 4; ++r) {
          int row = orow + r, col = nt*16 + ocol;
          float v = silu_f(acc[nt][r]);
          m_lds[row*MS + col] = f2bf(v);
          atomicAdd(&msg_tot[didx[row]*64 + col], v);
        }
      }
    }
    __syncthreads();
    // ---- GEMM3 + dot w2_mov: s = silu(msg @ W3) @ w2m ; scatter rel*s
    {
      const f32x4 z4 = {0.f, 0.f, 0.f, 0.f};
      f32x4 acc[4];
      #pragma unroll
      for (int nt = 0; nt < 4; ++nt) acc[nt] = z4;
      #pragma unroll
      for (int kb = 0; kb < 2; ++kb) {
        bf16x8 af = *(const bf16x8*)(m_lds + row16*MS + kb*32 + g8);
        #pragma unroll
        for (int nt = 0; nt < 4; ++nt) {
          bf16x8 bfv = *(const bf16x8*)(w3f + ((kb*4 + nt)*64 + lane)*8);
          acc[nt] = __builtin_amdgcn_mfma_f32_16x16x32_bf16(af, bfv, acc[nt], 0, 0, 0);
        }
      }
      float part[4] = {0.f, 0.f, 0.f, 0.f};
      #pragma unroll
      for (int nt = 0; nt < 4; ++nt) {
        float wm = w2m[nt*16 + (lane & 15)];
        #pragma unroll
        for (int r = 0; r < 4; ++r) part[r] += silu_f(acc[nt][r]) * wm;
      }
      #pragma unroll
      for (int off = 1; off < 16; off <<= 1) {
        #pragma unroll
        for (int r = 0; r < 4; ++r) part[r] += __shfl_xor(part[r], off, 64);
      }
      if ((lane & 15) == 0) {
        #pragma unroll
        for (int r = 0; r < 4; ++r) {
          int row = orow + r;
          float s = part[r];
          int d = didx[row];
          atomicAdd(&out_coord[d*3 + 0], relv[0][row] * s);
          atomicAdd(&out_coord[d*3 + 1], relv[1][row] * s);
          atomicAdd(&out_coord[d*3 + 2], relv[2][row] * s);
        }
      }
    }
  }
}

// ---------------------------------------------------------------------------
// Node kernel: new_feat = node_feat + silu([feat|total_msg]@W1n + b1)@W2n + b2
// ---------------------------------------------------------------------------
__global__ __launch_bounds__(256, 1) void egnn_node(
    const float* __restrict__ node_feat, const float* __restrict__ msg_tot,
    const float* __restrict__ w1n, const float* __restrict__ b1n,
    const float* __restrict__ w2n, const float* __restrict__ b2n,
    float* __restrict__ out_feat)
{
  __shared__ unsigned short w1f[4*8*64*8];   // 32KB
  __shared__ unsigned short w2f[4*4*64*8];   // 16KB
  __shared__ unsigned short a_lds[64*HS];
  __shared__ unsigned short h_lds[64*HS];
  __shared__ float b1s[128];
  __shared__ float b2s[64];

  const int t = threadIdx.x, lane = t & 63, wv = t >> 6;
  const int n0 = blockIdx.x * 64;
  const int row16 = wv*16 + (lane & 15);
  const int g8 = (lane >> 4) * 8;
  const int orow = wv*16 + (lane >> 4)*4;
  const int ocol = lane & 15;

  for (int i = t; i < 4*8*64*8; i += 256) {
    int j = i & 7, l = (i >> 3) & 63, nt = (i >> 9) & 7, kb = i >> 12;
    w1f[i] = f2bf(w1n[(kb*32 + (l >> 4)*8 + j)*128 + nt*16 + (l & 15)]);
  }
  for (int i = t; i < 4*4*64*8; i += 256) {
    int j = i & 7, l = (i >> 3) & 63, nt = (i >> 9) & 3, kb = i >> 11;
    w2f[i] = f2bf(w2n[(kb*32 + (l >> 4)*8 + j)*64 + nt*16 + (l & 15)]);
  }
  if (t < 128) b1s[t] = b1n[t];
  if (t < 64)  b2s[t] = b2n[t];

  {
    const int nd = t >> 2, q = t & 3;
    const int gn = n0 + nd;
    unsigned short* arow = a_lds + nd*HS;
    if (gn < NN) {
      const float4* pf = (const float4*)(node_feat + gn*64 + q*16);
      const float4* pm = (const float4*)(msg_tot + gn*64 + q*16);
      #pragma unroll
      for (int qq = 0; qq < 4; ++qq) {
        float4 v = pf[qq]; int c = q*16 + qq*4;
        arow[c] = f2bf(v.x); arow[c+1] = f2bf(v.y); arow[c+2] = f2bf(v.z); arow[c+3] = f2bf(v.w);
      }
      #pragma unroll
      for (int qq = 0; qq < 4; ++qq) {
        float4 v = pm[qq]; int c = 64 + q*16 + qq*4;
        arow[c] = f2bf(v.x); arow[c+1] = f2bf(v.y); arow[c+2] = f2bf(v.z); arow[c+3] = f2bf(v.w);
      }
    } else {
      #pragma unroll
      for (int c = 0; c < 16; ++c) { arow[q*16 + c] = 0; arow[64 + q*16 + c] = 0; }
    }
  }
  __syncthreads();
  {
    const f32x4 z4 = {0.f, 0.f, 0.f, 0.f};
    f32x4 acc[8];
    #pragma unroll
    for (int nt = 0; nt < 8; ++nt) acc[nt] = z4;
    #pragma unroll
    for (int kb = 0; kb < 4; ++kb) {
      bf16x8 af = *(const bf16x8*)(a_lds + row16*HS + kb*32 + g8);
      #pragma unroll
      for (int nt = 0; nt < 8; ++nt) {
        bf16x8 bfv = *(const bf16x8*)(w1f + ((kb*8 + nt)*64 + lane)*8);
        acc[nt] = __builtin_amdgcn_mfma_f32_16x16x32_bf16(af, bfv, acc[nt], 0, 0, 0);
      }
    }
    #pragma unroll
    for (int nt = 0; nt < 8; ++nt) {
      #pragma unroll
      for (int r = 0; r < 4; ++r) {
        int col = nt*16 + ocol;
        h_lds[(orow + r)*HS + col] = f2bf(silu_f(acc[nt][r] + b1s[col]));
      }
    }
  }
  __syncthreads();
  {
    const f32x4 z4 = {0.f, 0.f, 0.f, 0.f};
    f32x4 acc[4];
    #pragma unroll
    for (int nt = 0; nt < 4; ++nt) acc[nt] = z4;
    #pragma unroll
    for (int kb = 0; kb < 4; ++kb) {
      bf16x8 af = *(const bf16x8*)(h_lds + row16*HS + kb*32 + g8);
      #pragma unroll
      for (int nt = 0; nt < 4; ++nt) {
        bf16x8 bfv = *(const bf16x8*)(w2f + ((kb*4 + nt)*64 + lane)*8);
        acc[nt] = __builtin_amdgcn_mfma_f32_16x16x32_bf16(af, bfv, acc[nt], 0, 0, 0);
      }
    }
    #pragma unroll
    for (int nt = 0; nt < 4; ++nt) {
      #pragma unroll
      for (int r = 0; r < 4; ++r) {
        int row = orow + r, gn = n0 + row;
        if (gn < NN) {
          int col = nt*16 + ocol;
          out_feat[gn*64 + col] = acc[nt][r] + b2s[col] + node_feat[gn*64 + col];
        }
      }
    }
  }
}

extern "C" void kernel_launch(void* const* d_in, const int* in_sizes, int n_in,
                              void* d_out, int out_size, void* d_ws, size_t ws_size,
                              hipStream_t stream) {
  (void)in_sizes; (void)n_in; (void)out_size; (void)ws_size;
  const float* node_feat = (const float*)d_in[0];
  const float* coord     = (const float*)d_in[1];
  const float* edge_feat = (const float*)d_in[2];
  const int*   eidx      = (const int*)d_in[3];
  const float* w1_msg    = (const float*)d_in[4];
  const float* w2_msg    = (const float*)d_in[5];
  const float* w1_mov    = (const float*)d_in[6];
  const float* w2_mov    = (const float*)d_in[7];
  const float* rbf_c     = (const float*)d_in[8];
  const float* w1n       = (const float*)d_in[9];
  const float* b1n       = (const float*)d_in[10];
  const float* w2n       = (const float*)d_in[11];
  const float* b2n       = (const float*)d_in[12];

  float* out_feat  = (float*)d_out;
  float* out_coord = out_feat + (size_t)NN * 64;
  float* msg_tot   = (float*)d_ws;

  hipMemsetAsync(msg_tot, 0, (size_t)NN * 64 * sizeof(float), stream);
  hipMemcpyAsync(out_coord, coord, (size_t)NN * 3 * sizeof(float),
                 hipMemcpyDeviceToDevice, stream);
  egnn_edge<<<256, 256, 0, stream>>>(node_feat, coord, edge_feat, eidx,
      w1_msg, w2_msg, w1_mov, w2_mov, rbf_c, msg_tot, out_coord);
  egnn_node<<<(NN + 63) / 64, 256, 0, stream>>>(node_feat, msg_tot,
      w1n, b1n, w2n, b2n, out_feat);
}

// Round 3
// 708.420 us; speedup vs baseline: 1.4095x; 1.4095x over previous
//
#include <hip/hip_runtime.h>
#include <hip/hip_bf16.h>

#define E_TOT   1600000
#define NN      50000
#define K1      176     // msg MLP input dim (2*64+32+16)
#define H1      128     // MSG_HID
#define ROWS    32      // edges per wave-group (2 row-tiles of 16)
#define HS2     136     // act row stride (ushorts), 272B, 16B aligned
#define NG      (E_TOT / ROWS)

typedef __attribute__((ext_vector_type(8))) short bf16x8;
typedef __attribute__((ext_vector_type(4))) float f32x4;

__device__ __forceinline__ unsigned short f2bf(float x) {
  unsigned u = __builtin_bit_cast(unsigned, x);
  return (unsigned short)((u + 0x7FFFu + ((u >> 16) & 1u)) >> 16);   // RNE
}
__device__ __forceinline__ float silu_f(float x) { return x / (1.0f + __expf(-x)); }

__device__ __forceinline__ bf16x8 ldf8(const float* __restrict__ p) {
  float4 a = ((const float4*)p)[0];
  float4 b = ((const float4*)p)[1];
  bf16x8 r;
  r[0] = (short)f2bf(a.x); r[1] = (short)f2bf(a.y);
  r[2] = (short)f2bf(a.z); r[3] = (short)f2bf(a.w);
  r[4] = (short)f2bf(b.x); r[5] = (short)f2bf(b.y);
  r[6] = (short)f2bf(b.z); r[7] = (short)f2bf(b.w);
  return r;
}

// ---------------------------------------------------------------------------
// Edge kernel v3: barrier-free main loop (round-2 structure) + round-1-proven
// fp32 atomicAdd scatters (no inline-asm atomics, fp32 msg_tot).
// Each wave independently processes 32-edge groups. GEMM1 A-fragments come
// straight from global (gathers), rbf computed in-register; h and m live in
// wave-private LDS (aliased). Weights staged once to LDS (one barrier).
// Fragment convention (16x16x32 bf16): A elem j of lane l = A[l%16][(l/16)*8+j],
// B elem j = B[(l/16)*8+j][l%16] (same k-map => permutation-safe).
// C/D: col = lane&15, row = (lane>>4)*4 + reg   (HW-verified).
// ---------------------------------------------------------------------------
__global__ __launch_bounds__(512, 1) void egnn_edge(
    const float* __restrict__ node_feat, const float* __restrict__ coord,
    const float* __restrict__ edge_feat, const int* __restrict__ eidx,
    const float* __restrict__ w1_msg, const float* __restrict__ w2_msg,
    const float* __restrict__ w1_mov, const float* __restrict__ w2_mov,
    float* __restrict__ msg_tot, float* __restrict__ out_coord)
{
  __shared__ unsigned short w1f[6*8*64*8];     // 48KB  [kb<6][nt<8][lane][8]
  __shared__ unsigned short w2f[4*4*64*8];     // 16KB
  __shared__ unsigned short w3f[2*4*64*8];     // 8KB
  __shared__ unsigned short act[8][ROWS*HS2];  // 69.6KB, per-wave h (cols0..127) / m (cols0..63)

  const int t = threadIdx.x;
  const int lane = t & 63;
  const int wv = t >> 6;

  // ---- stage weight fragments (once per block) ----
  for (int i = t; i < 6*8*64*8; i += 512) {
    int j = i & 7, l = (i >> 3) & 63, nt = (i >> 9) & 7, kb = i >> 12;
    int k = kb*32 + (l >> 4)*8 + j;
    w1f[i] = f2bf(k < K1 ? w1_msg[k*H1 + nt*16 + (l & 15)] : 0.0f);
  }
  for (int i = t; i < 4*4*64*8; i += 512) {
    int j = i & 7, l = (i >> 3) & 63, nt = (i >> 9) & 3, kb = i >> 11;
    w2f[i] = f2bf(w2_msg[(kb*32 + (l >> 4)*8 + j)*64 + nt*16 + (l & 15)]);
  }
  for (int i = t; i < 2*4*64*8; i += 512) {
    int j = i & 7, l = (i >> 3) & 63, nt = (i >> 9) & 3, kb = i >> 11;
    w3f[i] = f2bf(w1_mov[(kb*32 + (l >> 4)*8 + j)*64 + nt*16 + (l & 15)]);
  }

  const int cl = lane & 15;           // A row within 16-tile / C col
  const int g8 = (lane >> 4) * 8;     // k sub-offset
  const int orow4 = (lane >> 4) * 4;  // C row base within 16-tile
  float w2m_r[4];
  #pragma unroll
  for (int nt = 0; nt < 4; ++nt) w2m_r[nt] = w2_mov[nt*16 + cl];

  __syncthreads();                    // weights ready; no barriers after this

  unsigned short* const myact = &act[wv][0];
  const int NW = gridDim.x * 8;

  for (int g = blockIdx.x * 8 + wv; g < NG; g += NW) {
    const int e0 = g * ROWS;
    // ---- indices + geometry (lanes duplicated over upper half) ----
    const int el = lane & 31;
    int sv = eidx[e0 + el];
    int dv = eidx[E_TOT + e0 + el];
    float rx = coord[dv*3+0] - coord[sv*3+0];
    float ry = coord[dv*3+1] - coord[sv*3+1];
    float rz = coord[dv*3+2] - coord[sv*3+2];
    float dist = sqrtf(rx*rx + ry*ry + rz*rz);

    const int s0 = __shfl(sv, cl),      s1 = __shfl(sv, 16 + cl);
    const int d0 = __shfl(dv, cl),      d1 = __shfl(dv, 16 + cl);
    const float dist0 = __shfl(dist, cl), dist1 = __shfl(dist, 16 + cl);

    // ---- GEMM1: h = silu(m_in @ W1)  [32x192]@[192x128] ----
    f32x4 acc1[2][8];
    #pragma unroll
    for (int rt = 0; rt < 2; ++rt)
      #pragma unroll
      for (int nt = 0; nt < 8; ++nt) acc1[rt][nt] = (f32x4){0.f,0.f,0.f,0.f};
    #pragma unroll
    for (int kb = 0; kb < 6; ++kb) {
      bf16x8 af0, af1;
      if (kb < 2) {
        af0 = ldf8(node_feat + (size_t)s0*64 + kb*32 + g8);
        af1 = ldf8(node_feat + (size_t)s1*64 + kb*32 + g8);
      } else if (kb < 4) {
        af0 = ldf8(node_feat + (size_t)d0*64 + (kb-2)*32 + g8);
        af1 = ldf8(node_feat + (size_t)d1*64 + (kb-2)*32 + g8);
      } else if (kb == 4) {           // rbf: centers c_i = i*10/31, i = g8+j
        #pragma unroll
        for (int j = 0; j < 8; ++j) {
          float c = (float)(g8 + j) * (10.0f / 31.0f);
          float u0 = dist0 - c, u1 = dist1 - c;
          af0[j] = (short)f2bf(__expf(-10.0f * u0 * u0));
          af1[j] = (short)f2bf(__expf(-10.0f * u1 * u1));
        }
      } else {                        // edge_feat cols 160..175 + zero pad
        if (g8 < 16) {
          af0 = ldf8(edge_feat + (size_t)(e0 + cl) * 16 + g8);
          af1 = ldf8(edge_feat + (size_t)(e0 + 16 + cl) * 16 + g8);
        } else {
          af0 = (bf16x8){0,0,0,0,0,0,0,0};
          af1 = af0;
        }
      }
      #pragma unroll
      for (int nt = 0; nt < 8; ++nt) {
        bf16x8 bw = *(const bf16x8*)(w1f + ((kb*8 + nt)*64 + lane)*8);
        acc1[0][nt] = __builtin_amdgcn_mfma_f32_16x16x32_bf16(af0, bw, acc1[0][nt], 0, 0, 0);
        acc1[1][nt] = __builtin_amdgcn_mfma_f32_16x16x32_bf16(af1, bw, acc1[1][nt], 0, 0, 0);
      }
    }
    #pragma unroll
    for (int rt = 0; rt < 2; ++rt)
      #pragma unroll
      for (int nt = 0; nt < 8; ++nt)
        #pragma unroll
        for (int r = 0; r < 4; ++r)
          myact[(rt*16 + orow4 + r)*HS2 + nt*16 + cl] = f2bf(silu_f(acc1[rt][nt][r]));
    asm volatile("" ::: "memory");    // keep h-writes before h-reads (compiler order)

    // ---- GEMM2: msg = silu(h @ W2)  [32x128]@[128x64] ----
    f32x4 acc2[2][4];
    #pragma unroll
    for (int rt = 0; rt < 2; ++rt)
      #pragma unroll
      for (int nt = 0; nt < 4; ++nt) acc2[rt][nt] = (f32x4){0.f,0.f,0.f,0.f};
    #pragma unroll
    for (int kb = 0; kb < 4; ++kb) {
      bf16x8 a0 = *(const bf16x8*)(myact + cl*HS2 + kb*32 + g8);
      bf16x8 a1 = *(const bf16x8*)(myact + (16 + cl)*HS2 + kb*32 + g8);
      #pragma unroll
      for (int nt = 0; nt < 4; ++nt) {
        bf16x8 bw = *(const bf16x8*)(w2f + ((kb*4 + nt)*64 + lane)*8);
        acc2[0][nt] = __builtin_amdgcn_mfma_f32_16x16x32_bf16(a0, bw, acc2[0][nt], 0, 0, 0);
        acc2[1][nt] = __builtin_amdgcn_mfma_f32_16x16x32_bf16(a1, bw, acc2[1][nt], 0, 0, 0);
      }
    }
    asm volatile("" ::: "memory");
    // m -> act cols 0..63 (overwrites h cols 0..63; all h reads already issued)
    // + direct fp32 atomic scatter of msg from accumulator registers
    {
      int drr[2][4];
      #pragma unroll
      for (int rt = 0; rt < 2; ++rt)
        #pragma unroll
        for (int r = 0; r < 4; ++r)
          drr[rt][r] = __shfl(dv, rt*16 + orow4 + r);
      #pragma unroll
      for (int rt = 0; rt < 2; ++rt)
        #pragma unroll
        for (int nt = 0; nt < 4; ++nt)
          #pragma unroll
          for (int r = 0; r < 4; ++r) {
            float v = silu_f(acc2[rt][nt][r]);
            myact[(rt*16 + orow4 + r)*HS2 + nt*16 + cl] = f2bf(v);
            atomicAdd(&msg_tot[(size_t)drr[rt][r]*64 + nt*16 + cl], v);
          }
    }
    asm volatile("" ::: "memory");    // keep m-writes before m-reads

    // ---- GEMM3: s = silu(msg @ W3) @ w2_mov ; mov scatter ----
    f32x4 acc3[2][4];
    #pragma unroll
    for (int rt = 0; rt < 2; ++rt)
      #pragma unroll
      for (int nt = 0; nt < 4; ++nt) acc3[rt][nt] = (f32x4){0.f,0.f,0.f,0.f};
    #pragma unroll
    for (int kb = 0; kb < 2; ++kb) {
      bf16x8 a0 = *(const bf16x8*)(myact + cl*HS2 + kb*32 + g8);
      bf16x8 a1 = *(const bf16x8*)(myact + (16 + cl)*HS2 + kb*32 + g8);
      #pragma unroll
      for (int nt = 0; nt < 4; ++nt) {
        bf16x8 bw = *(const bf16x8*)(w3f + ((kb*4 + nt)*64 + lane)*8);
        acc3[0][nt] = __builtin_amdgcn_mfma_f32_16x16x32_bf16(a0, bw, acc3[0][nt], 0, 0, 0);
        acc3[1][nt] = __builtin_amdgcn_mfma_f32_16x16x32_bf16(a1, bw, acc3[1][nt], 0, 0, 0);
      }
    }
    float prt[2][4];
    #pragma unroll
    for (int rt = 0; rt < 2; ++rt)
      #pragma unroll
      for (int r = 0; r < 4; ++r) prt[rt][r] = 0.f;
    #pragma unroll
    for (int nt = 0; nt < 4; ++nt)
      #pragma unroll
      for (int rt = 0; rt < 2; ++rt)
        #pragma unroll
        for (int r = 0; r < 4; ++r)
          prt[rt][r] += silu_f(acc3[rt][nt][r]) * w2m_r[nt];
    #pragma unroll
    for (int off = 1; off < 16; off <<= 1)
      #pragma unroll
      for (int rt = 0; rt < 2; ++rt)
        #pragma unroll
        for (int r = 0; r < 4; ++r) prt[rt][r] += __shfl_xor(prt[rt][r], off, 64);
    #pragma unroll
    for (int rt = 0; rt < 2; ++rt)
      #pragma unroll
      for (int r = 0; r < 4; ++r) {
        int row = rt*16 + orow4 + r;
        float rxr = __shfl(rx, row), ryr = __shfl(ry, row), rzr = __shfl(rz, row);
        int   dr  = __shfl(dv, row);
        if (cl == 0) {
          float s = prt[rt][r];
          atomicAdd(&out_coord[(size_t)dr*3 + 0], rxr * s);
          atomicAdd(&out_coord[(size_t)dr*3 + 1], ryr * s);
          atomicAdd(&out_coord[(size_t)dr*3 + 2], rzr * s);
        }
      }
  }
}

// ---------------------------------------------------------------------------
// Node kernel: new_feat = node_feat + silu([feat|total_msg]@W1n + b1)@W2n + b2
// ---------------------------------------------------------------------------
__global__ __launch_bounds__(256, 1) void egnn_node(
    const float* __restrict__ node_feat, const float* __restrict__ msg_tot,
    const float* __restrict__ w1n, const float* __restrict__ b1n,
    const float* __restrict__ w2n, const float* __restrict__ b2n,
    float* __restrict__ out_feat)
{
  __shared__ unsigned short w1f[4*8*64*8];   // 32KB
  __shared__ unsigned short w2f[4*4*64*8];   // 16KB
  __shared__ unsigned short a_lds[64*HS2];
  __shared__ unsigned short h_lds[64*HS2];
  __shared__ float b1s[128];
  __shared__ float b2s[64];

  const int t = threadIdx.x, lane = t & 63, wv = t >> 6;
  const int n0 = blockIdx.x * 64;
  const int row16 = wv*16 + (lane & 15);
  const int g8 = (lane >> 4) * 8;
  const int orow = wv*16 + (lane >> 4)*4;
  const int ocol = lane & 15;

  for (int i = t; i < 4*8*64*8; i += 256) {
    int j = i & 7, l = (i >> 3) & 63, nt = (i >> 9) & 7, kb = i >> 12;
    w1f[i] = f2bf(w1n[(kb*32 + (l >> 4)*8 + j)*128 + nt*16 + (l & 15)]);
  }
  for (int i = t; i < 4*4*64*8; i += 256) {
    int j = i & 7, l = (i >> 3) & 63, nt = (i >> 9) & 3, kb = i >> 11;
    w2f[i] = f2bf(w2n[(kb*32 + (l >> 4)*8 + j)*64 + nt*16 + (l & 15)]);
  }
  if (t < 128) b1s[t] = b1n[t];
  if (t < 64)  b2s[t] = b2n[t];

  {
    const int nd = t >> 2, q = t & 3;
    const int gn = n0 + nd;
    unsigned short* arow = a_lds + nd*HS2;
    if (gn < NN) {
      const float4* pf = (const float4*)(node_feat + (size_t)gn*64 + q*16);
      const float4* pm = (const float4*)(msg_tot + (size_t)gn*64 + q*16);
      #pragma unroll
      for (int qq = 0; qq < 4; ++qq) {
        float4 v = pf[qq]; int c = q*16 + qq*4;
        arow[c] = f2bf(v.x); arow[c+1] = f2bf(v.y); arow[c+2] = f2bf(v.z); arow[c+3] = f2bf(v.w);
      }
      #pragma unroll
      for (int qq = 0; qq < 4; ++qq) {
        float4 v = pm[qq]; int c = 64 + q*16 + qq*4;
        arow[c] = f2bf(v.x); arow[c+1] = f2bf(v.y); arow[c+2] = f2bf(v.z); arow[c+3] = f2bf(v.w);
      }
    } else {
      #pragma unroll
      for (int c = 0; c < 16; ++c) { arow[q*16 + c] = 0; arow[64 + q*16 + c] = 0; }
    }
  }
  __syncthreads();
  {
    f32x4 acc[8];
    #pragma unroll
    for (int nt = 0; nt < 8; ++nt) acc[nt] = (f32x4){0.f,0.f,0.f,0.f};
    #pragma unroll
    for (int kb = 0; kb < 4; ++kb) {
      bf16x8 af = *(const bf16x8*)(a_lds + row16*HS2 + kb*32 + g8);
      #pragma unroll
      for (int nt = 0; nt < 8; ++nt) {
        bf16x8 bfv = *(const bf16x8*)(w1f + ((kb*8 + nt)*64 + lane)*8);
        acc[nt] = __builtin_amdgcn_mfma_f32_16x16x32_bf16(af, bfv, acc[nt], 0, 0, 0);
      }
    }
    #pragma unroll
    for (int nt = 0; nt < 8; ++nt)
      #pragma unroll
      for (int r = 0; r < 4; ++r) {
        int col = nt*16 + ocol;
        h_lds[(orow + r)*HS2 + col] = f2bf(silu_f(acc[nt][r] + b1s[col]));
      }
  }
  __syncthreads();
  {
    f32x4 acc[4];
    #pragma unroll
    for (int nt = 0; nt < 4; ++nt) acc[nt] = (f32x4){0.f,0.f,0.f,0.f};
    #pragma unroll
    for (int kb = 0; kb < 4; ++kb) {
      bf16x8 af = *(const bf16x8*)(h_lds + row16*HS2 + kb*32 + g8);
      #pragma unroll
      for (int nt = 0; nt < 4; ++nt) {
        bf16x8 bfv = *(const bf16x8*)(w2f + ((kb*4 + nt)*64 + lane)*8);
        acc[nt] = __builtin_amdgcn_mfma_f32_16x16x32_bf16(af, bfv, acc[nt], 0, 0, 0);
      }
    }
    #pragma unroll
    for (int nt = 0; nt < 4; ++nt)
      #pragma unroll
      for (int r = 0; r < 4; ++r) {
        int row = orow + r, gn = n0 + row;
        if (gn < NN) {
          int col = nt*16 + ocol;
          out_feat[(size_t)gn*64 + col] = acc[nt][r] + b2s[col] + node_feat[(size_t)gn*64 + col];
        }
      }
  }
}

extern "C" void kernel_launch(void* const* d_in, const int* in_sizes, int n_in,
                              void* d_out, int out_size, void* d_ws, size_t ws_size,
                              hipStream_t stream) {
  (void)in_sizes; (void)n_in; (void)out_size; (void)ws_size;
  const float* node_feat = (const float*)d_in[0];
  const float* coord     = (const float*)d_in[1];
  const float* edge_feat = (const float*)d_in[2];
  const int*   eidx      = (const int*)d_in[3];
  const float* w1_msg    = (const float*)d_in[4];
  const float* w2_msg    = (const float*)d_in[5];
  const float* w1_mov    = (const float*)d_in[6];
  const float* w2_mov    = (const float*)d_in[7];
  const float* w1n       = (const float*)d_in[9];
  const float* b1n       = (const float*)d_in[10];
  const float* w2n       = (const float*)d_in[11];
  const float* b2n       = (const float*)d_in[12];

  float* out_feat  = (float*)d_out;
  float* out_coord = out_feat + (size_t)NN * 64;
  float* msg_tot   = (float*)d_ws;

  hipMemsetAsync(msg_tot, 0, (size_t)NN * 64 * sizeof(float), stream);
  hipMemcpyAsync(out_coord, coord, (size_t)NN * 3 * sizeof(float),
                 hipMemcpyDeviceToDevice, stream);
  egnn_edge<<<256, 512, 0, stream>>>(node_feat, coord, edge_feat, eidx,
      w1_msg, w2_msg, w1_mov, w2_mov, msg_tot, out_coord);
  egnn_node<<<(NN + 63) / 64, 256, 0, stream>>>(node_feat, msg_tot,
      w1n, b1n, w2n, b2n, out_feat);
}